// Round 1
// 195.247 us; speedup vs baseline: 1.0050x; 1.0050x over previous
//
#include <hip/hip_runtime.h>
#include <hip/hip_bf16.h>
#include <math.h>

typedef unsigned short u16;
typedef unsigned int   u32;
using bf16x8 = __attribute__((ext_vector_type(8))) short;   // 8 bf16 (4 VGPRs)
using f32x4  = __attribute__((ext_vector_type(4))) float;   // MFMA C/D frag
using f32x16 = __attribute__((ext_vector_type(16))) float;  // 32x32 C/D frag
using u32v4  = __attribute__((ext_vector_type(4))) u32;

#define TE 256
#define TH 8
#define TS 2048
#define TB 4
#define NTOK 8192
// (1/sqrt(32)) * log2(e): folded into Q so softmax is pure exp2
#define QSCALE 0.2550120651552454f
#define EXP2(x) __builtin_amdgcn_exp2f(x)

__device__ __forceinline__ void async16(const u16* g, u16* l) {
    __builtin_amdgcn_global_load_lds(
        (const __attribute__((address_space(1))) u32*)g,
        (__attribute__((address_space(3))) u32*)l, 16, 0, 0);
}
// pack 2 floats -> 2 bf16 (round-half-up): 2 adds + v_perm
__device__ __forceinline__ u32 pkbf(float a, float b) {
    u32 ua = __float_as_uint(a) + 0x8000u;
    u32 ub = __float_as_uint(b) + 0x8000u;
    return __builtin_amdgcn_perm(ub, ua, 0x07060302u);  // [ub.b3 ub.b2 ua.b3 ua.b2]
}
__device__ __forceinline__ u16 bf1(float a) {
    return (u16)((__float_as_uint(a) + 0x8000u) >> 16);
}

// ---------------- LayerNorm: one wave per row, bf16 output -----------------
__global__ __launch_bounds__(256) void ln_bf(const float* __restrict__ in,
        u16* __restrict__ out, const float* __restrict__ gamma,
        const float* __restrict__ beta) {
    int row  = blockIdx.x * 4 + (threadIdx.x >> 6);
    int lane = threadIdx.x & 63;
    float4 v = ((const float4*)(in + (size_t)row * TE))[lane];
    float s  = v.x + v.y + v.z + v.w;
    float s2 = v.x*v.x + v.y*v.y + v.z*v.z + v.w*v.w;
    #pragma unroll
    for (int off = 32; off > 0; off >>= 1) {
        s  += __shfl_down(s,  off, 64);
        s2 += __shfl_down(s2, off, 64);
    }
    s  = __shfl(s,  0, 64);
    s2 = __shfl(s2, 0, 64);
    float mu = s * (1.f / TE);
    float rs = rsqrtf(s2 * (1.f / TE) - mu * mu + 1e-5f);
    float4 g = ((const float4*)gamma)[lane];
    float4 b = ((const float4*)beta )[lane];
    u32 lo = pkbf((v.x - mu) * rs * g.x + b.x, (v.y - mu) * rs * g.y + b.y);
    u32 hi = pkbf((v.z - mu) * rs * g.z + b.z, (v.w - mu) * rs * g.w + b.w);
    ((uint2*)(out + (size_t)row * TE))[lane] = make_uint2(lo, hi);
}

// -------------- convert the 4 weight matrices fp32 -> bf16 -----------------
__global__ __launch_bounds__(256) void convw(const float* __restrict__ s0, u16* d0,
        const float* __restrict__ s1, u16* d1, const float* __restrict__ s2, u16* d2,
        const float* __restrict__ s3, u16* d3) {
    int i = (blockIdx.x * 256 + threadIdx.x) * 4;
    const float* s; u16* d;
    if      (i < 196608) { s = s0; d = d0; }
    else if (i < 262144) { s = s1; d = d1; i -= 196608; }
    else if (i < 524288) { s = s2; d = d2; i -= 262144; }
    else                 { s = s3; d = d3; i -= 524288; }
    float4 v = *(const float4*)(s + i);
    *(uint2*)(d + i) = make_uint2(pkbf(v.x, v.y), pkbf(v.z, v.w));
}

// ------------------- MFMA GEMM: C[N,M] = A[N,K] @ W[M,K]^T -----------------
// BK=64 staged as two 32-halves per barrier pair (half the barrier drains).
// BM=BN=128: 4 waves x (64tok x 64feat). BM=BN=64: 4 waves x (32tok x 32feat)
// Operands swapped (D rows=feat, cols=tok) -> lane holds 4 consecutive feats.
// EPI: 0=QKV: feats<512 -> bf16 [tok][512] (+qscale feat<256); feats>=512 ->
// V^T bf16 [bh][d][2048] (Cf carries the V^T pointer); 1=fp32 +residual;
// 2=bf16 relu(acc+bias); 3=fp32 acc+bias+residual.
template<int K, int BM, int EPI>
__global__ __launch_bounds__(256) void mgemm(const u16* __restrict__ A,
        const u16* __restrict__ W, const float* __restrict__ bias,
        const float* __restrict__ R, float* __restrict__ Cf,
        u16* __restrict__ Cb, int M) {
    constexpr int BN = BM;                       // square tiles
    __shared__ u16 Al[2][BM * 32];
    __shared__ u16 Wl[2][BN * 32];
    const int tid = threadIdx.x, w = tid >> 6, l = tid & 63;
    const int n0 = blockIdx.y * BM;              // token base
    const int m0 = blockIdx.x * BN;              // feat base
    constexpr int NT = (BM == 128) ? 4 : 2;      // tok frags / wave
    constexpr int NF = (BM == 128) ? 4 : 2;      // feat frags / wave
    const int tw = (w & 1) * NT * 16;
    const int fw = (w >> 1) * NF * 16;
    const int fr = l & 15, fq = l >> 4;
    const int sr = l >> 2, sc = (l & 3) * 8;
    f32x4 acc[NT][NF];
    #pragma unroll
    for (int t = 0; t < NT; t++)
        #pragma unroll
        for (int f = 0; f < NF; f++)
            #pragma unroll
            for (int r = 0; r < 4; r++) acc[t][f][r] = 0.f;

    for (int k0 = 0; k0 < K; k0 += 64) {
        __syncthreads();
        #pragma unroll
        for (int hh = 0; hh < 2; hh++) {
            const int kc = k0 + hh * 32;
            if (BM == 128) {
                #pragma unroll
                for (int c = 0; c < 2; c++) {
                    int rr = (w * 2 + c) * 16 + sr;
                    async16(A + (size_t)(n0 + rr) * K + kc + sc, &Al[hh][(w * 2 + c) * 512]);
                    async16(W + (size_t)(m0 + rr) * K + kc + sc, &Wl[hh][(w * 2 + c) * 512]);
                }
            } else {
                int rr = w * 16 + sr;
                async16(A + (size_t)(n0 + rr) * K + kc + sc, &Al[hh][w * 512]);
                async16(W + (size_t)(m0 + rr) * K + kc + sc, &Wl[hh][w * 512]);
            }
        }
        __syncthreads();
        #pragma unroll
        for (int hh = 0; hh < 2; hh++) {
            bf16x8 af[NT], wf[NF];
            #pragma unroll
            for (int t = 0; t < NT; t++)
                af[t] = *(const bf16x8*)&Al[hh][(tw + t * 16 + fr) * 32 + fq * 8];
            #pragma unroll
            for (int f = 0; f < NF; f++)
                wf[f] = *(const bf16x8*)&Wl[hh][(fw + f * 16 + fr) * 32 + fq * 8];
            #pragma unroll
            for (int t = 0; t < NT; t++)
                #pragma unroll
                for (int f = 0; f < NF; f++)
                    acc[t][f] = __builtin_amdgcn_mfma_f32_16x16x32_bf16(
                        wf[f], af[t], acc[t][f], 0, 0, 0);   // D rows=feat, cols=tok
        }
    }
    // epilogue: lane holds (tok = n0+tw+t*16+fr, feats fb..fb+3)
    #pragma unroll
    for (int t = 0; t < NT; t++) {
        const int tok = n0 + tw + t * 16 + fr;
        #pragma unroll
        for (int f = 0; f < NF; f++) {
            const int fb = m0 + fw + f * 16 + fq * 4;
            f32x4 v = acc[t][f];
            if (EPI == 0) {
                if (fb < 512) {
                    const float qs = (fb < 256) ? QSCALE : 1.f;
                    *(uint2*)(Cb + (size_t)tok * 512 + fb) =
                        make_uint2(pkbf(v[0]*qs, v[1]*qs), pkbf(v[2]*qs, v[3]*qs));
                } else {
                    // V^T: [bh][d=32][kv=2048]
                    const int hh = (fb - 512) >> 5, dd = (fb - 512) & 31;
                    u16* vt = (u16*)Cf +
                        ((size_t)((tok >> 11) * 8 + hh) * 32 + dd) * 2048 + (tok & 2047);
                    vt[0]    = bf1(v[0]);
                    vt[2048] = bf1(v[1]);
                    vt[4096] = bf1(v[2]);
                    vt[6144] = bf1(v[3]);
                }
            } else if (EPI == 1) {
                float4 r4 = *(const float4*)(R + (size_t)tok * M + fb);
                *(float4*)(Cf + (size_t)tok * M + fb) =
                    make_float4(v[0]+r4.x, v[1]+r4.y, v[2]+r4.z, v[3]+r4.w);
            } else if (EPI == 2) {
                float4 b4 = *(const float4*)(bias + fb);
                *(uint2*)(Cb + (size_t)tok * M + fb) = make_uint2(
                    pkbf(fmaxf(v[0]+b4.x, 0.f), fmaxf(v[1]+b4.y, 0.f)),
                    pkbf(fmaxf(v[2]+b4.z, 0.f), fmaxf(v[3]+b4.w, 0.f)));
            } else {
                float4 b4 = *(const float4*)(bias + fb);
                float4 r4 = *(const float4*)(R + (size_t)tok * M + fb);
                *(float4*)(Cf + (size_t)tok * M + fb) = make_float4(
                    v[0]+b4.x+r4.x, v[1]+b4.y+r4.y, v[2]+b4.z+r4.z, v[3]+b4.w+r4.w);
            }
        }
    }
}

// ------------- MFMA flash attention, in-register softmax (T12) -------------
// 32x32x16 MFMAs, swapped QK^T (mfma(K,Q)): lane (col=q=l&31) holds 16 P
// values (rows kv=(reg&3)+8*(reg>>2)+4*(l>>5)).  P -> bf16 PV-fragment fully
// in-register: 8 v_cvt_pk_bf16_f32 + 4 v_permlane32_swap_b32 (no P LDS).
// V is pre-transposed to global V^T[bh][d][kv] by the QKV-GEMM epilogue, so
// K, Q, V fragments are all direct 16B global loads (L2-resident; lo/hi lane
// pairs share 64B lines).  No LDS / barriers in the main loop.  kv-split 2:
// waves (qw=w&1, kw=w>>1); unnormalized partials merge by addition in LDS.
// Block swizzle pins all 32 blocks of one (b,h) to a single XCD (L2 reuse).
__global__ __launch_bounds__(256, 4) void attn_k(const u16* __restrict__ qk,
        const u16* __restrict__ vt, u16* __restrict__ attn) {
    const int id = blockIdx.x;                 // 1024 blocks
    const int bh   = (id & 7) * 4 + (id >> 8); // xcd*4 + group
    const int tile = (id >> 3) & 31;           // 64-q tile within bh
    const int b = bh >> 3, h = bh & 7;
    const int tid = threadIdx.x, w = tid >> 6, l = tid & 63;
    const int qw = w & 1, kw = w >> 1;
    const int lq = l & 31, hi = l >> 5;
    const size_t btok = (size_t)b * TS;
    const int q0 = tile * 64 + qw * 32;

    __shared__ float mrg[2304];                // 2 x 64 lanes x 18 f32

    // Q frags: B-op [col=q=l&31][k=d=(l>>5)*8..+8], pre-scaled by QSCALE
    const u16* qrow = qk + (btok + q0 + lq) * 512 + h * 32 + hi * 8;
    bf16x8 qf0 = *(const bf16x8*)qrow;         // d 0..16
    bf16x8 qf1 = *(const bf16x8*)(qrow + 16);  // d 16..32

    // K: A-op [row=kv=l&31][k=d]; V^T: A-op [row=d=l&31][k=kv]
    const u16* kb = qk + (btok + (size_t)kw * 1024) * 512 + 256 + h * 32 + hi * 8;
    const u16* vb = vt + ((size_t)bh * 32 + lq) * 2048 + kw * 1024 + hi * 8;

    f32x16 zf, o;
    #pragma unroll
    for (int r = 0; r < 16; r++) { zf[r] = 0.f; o[r] = 0.f; }
    float ps = 0.f;

    u32 koff = (u32)lq * 512;                  // u16 units
    u32 voff = 0;
    for (int it = 0; it < 32; ++it) {
        bf16x8 kf0 = *(const bf16x8*)(kb + koff);
        bf16x8 kf1 = *(const bf16x8*)(kb + koff + 16);
        bf16x8 vf0 = *(const bf16x8*)(vb + voff);
        bf16x8 vf1 = *(const bf16x8*)(vb + voff + 16);
        koff += 32 * 512;
        voff += 32;
        // S[kv][q] (col=q): two chained MFMAs cover d=32
        f32x16 p = __builtin_amdgcn_mfma_f32_32x32x16_bf16(kf0, qf0, zf, 0, 0, 0);
        p = __builtin_amdgcn_mfma_f32_32x32x16_bf16(kf1, qf1, p, 0, 0, 0);
        float e[16];
        #pragma unroll
        for (int r = 0; r < 16; r++) e[r] = EXP2(p[r]);
        ps += ((e[0]+e[1]) + (e[2]+e[3])) + ((e[4]+e[5]) + (e[6]+e[7]))
            + ((e[8]+e[9]) + (e[10]+e[11])) + ((e[12]+e[13]) + (e[14]+e[15]));
        // pack: a[j] = bf16(e[2j]) | bf16(e[2j+1])<<16  (kv-consecutive pairs)
        u32 a[8];
        #pragma unroll
        for (int j = 0; j < 8; j++)
            asm("v_cvt_pk_bf16_f32 %0, %1, %2"
                : "=v"(a[j]) : "v"(e[2*j]), "v"(e[2*j+1]));
        // redistribute across lane halves: (w0,w2)=swap(a0,a2) etc (T12)
        asm("v_permlane32_swap_b32 %0, %1" : "+v"(a[0]), "+v"(a[2]));
        asm("v_permlane32_swap_b32 %0, %1" : "+v"(a[1]), "+v"(a[3]));
        asm("v_permlane32_swap_b32 %0, %1" : "+v"(a[4]), "+v"(a[6]));
        asm("v_permlane32_swap_b32 %0, %1" : "+v"(a[5]), "+v"(a[7]));
        u32v4 t0 = {a[0], a[1], a[2], a[3]};   // P^T[q][kv0+hi*8 .. +8]
        u32v4 t1 = {a[4], a[5], a[6], a[7]};   // P^T[q][kv0+16+hi*8 .. +8]
        bf16x8 pf0 = __builtin_bit_cast(bf16x8, t0);
        bf16x8 pf1 = __builtin_bit_cast(bf16x8, t1);
        // O^T[d][q] += V^T * P^T
        o = __builtin_amdgcn_mfma_f32_32x32x16_bf16(vf0, pf0, o, 0, 0, 0);
        o = __builtin_amdgcn_mfma_f32_32x32x16_bf16(vf1, pf1, o, 0, 0, 0);
    }
    // lane l and l+32 (same q) cover complementary kv rows -> full half-sum
    ps += __shfl_xor(ps, 32, 64);

    // merge the two kv halves: kw=1 dumps (o, ps); kw=0 adds + stores
    if (kw == 1) {
        float* d = mrg + (qw * 64 + l) * 18;
        #pragma unroll
        for (int r = 0; r < 16; r++) d[r] = o[r];
        d[16] = ps;
    }
    __syncthreads();
    if (kw == 0) {
        const float* d = mrg + (qw * 64 + l) * 18;
        #pragma unroll
        for (int r = 0; r < 16; r++) o[r] += d[r];
        ps += d[16];
        float inv = 1.f / ps;
        // o reg r -> d = 8*(r>>2) + 4*hi + (r&3); q = lq
        int tok = (int)btok + q0 + lq;
        u16* orow = attn + (size_t)tok * 256 + h * 32 + hi * 4;
        #pragma unroll
        for (int g = 0; g < 4; g++)
            *(uint2*)(orow + g * 8) = make_uint2(
                pkbf(o[4*g]*inv, o[4*g+1]*inv), pkbf(o[4*g+2]*inv, o[4*g+3]*inv));
    }
}

extern "C" void kernel_launch(void* const* d_in, const int* in_sizes, int n_in,
                              void* d_out, int out_size, void* d_ws, size_t ws_size,
                              hipStream_t stream) {
    const float* src  = (const float*)d_in[0];
    const float* w_in = (const float*)d_in[1];
    const float* w_out= (const float*)d_in[2];
    const float* w1   = (const float*)d_in[3];
    const float* b1   = (const float*)d_in[4];
    const float* w2   = (const float*)d_in[5];
    const float* b2   = (const float*)d_in[6];
    const float* g1   = (const float*)d_in[7];
    const float* be1  = (const float*)d_in[8];
    const float* g2   = (const float*)d_in[9];
    const float* be2  = (const float*)d_in[10];
    float* out = (float*)d_out;

    u16* xb    = (u16*)d_ws;                       // [0, 4MB)    8192 x 256
    u16* qkb   = xb + (size_t)NTOK * 256;          // [4, 12MB)   8192 x 512 (Q|K)
    u16* vtb   = qkb + (size_t)NTOK * 512;         // [12, 16MB)  32 x 32 x 2048 V^T
    u16* attnb = xb;                               // reuse (xb dead after G2)
    u16* h1b   = (u16*)d_ws;                       // 8192*1024 (after attn GEMMs)
    u16* x2b   = (u16*)((char*)d_ws + (size_t)NTOK * 1024 * 2);
    u16* wib   = x2b + (size_t)NTOK * 256;
    u16* wob   = wib + 768 * 256;
    u16* w1b   = wob + 256 * 256;
    u16* w2b   = w1b + 1024 * 256;

    convw<<<768, 256, 0, stream>>>(w_in, wib, w_out, wob, w1, w1b, w2, w2b);
    // 1. xb = LN1(src) -> bf16
    ln_bf<<<NTOK / 4, 256, 0, stream>>>(src, xb, g1, be1);
    // 2. qkb = [Q|K] (Q scaled), vtb = V^T    (= xb @ w_in^T)
    mgemm<256, 128, 0><<<dim3(6, 64), 256, 0, stream>>>(
        xb, wib, nullptr, nullptr, (float*)vtb, qkb, 768);
    // 3. attnb = flash-attention(qkb, vtb)
    attn_k<<<dim3(1024), 256, 0, stream>>>(qkb, vtb, attnb);
    // 4. out = src + attnb @ w_out^T (fp32)
    mgemm<256, 64, 1><<<dim3(4, 128), 256, 0, stream>>>(
        attnb, wob, nullptr, src, out, nullptr, 256);
    // 5. x2b = LN2(out) -> bf16
    ln_bf<<<NTOK / 4, 256, 0, stream>>>(out, x2b, g2, be2);
    // 6. h1b = relu(x2b @ w1^T + b1) -> bf16
    mgemm<256, 128, 2><<<dim3(8, 64), 256, 0, stream>>>(
        x2b, w1b, b1, nullptr, nullptr, h1b, 1024);
    // 7. out = out + h1b @ w2^T + b2 (fp32)
    mgemm<1024, 64, 3><<<dim3(4, 128), 256, 0, stream>>>(
        h1b, w2b, b2, out, out, nullptr, 256);
}

// Round 2
// 160.923 us; speedup vs baseline: 1.2194x; 1.2133x over previous
//
#include <hip/hip_runtime.h>
#include <hip/hip_bf16.h>
#include <math.h>

typedef unsigned short u16;
typedef unsigned int   u32;
using bf16x8 = __attribute__((ext_vector_type(8))) short;   // 8 bf16 (4 VGPRs)
using f32x4  = __attribute__((ext_vector_type(4))) float;   // MFMA C/D frag
using f32x16 = __attribute__((ext_vector_type(16))) float;  // 32x32 C/D frag
using u32v4  = __attribute__((ext_vector_type(4))) u32;

#define TE 256
#define TH 8
#define TS 2048
#define TB 4
#define NTOK 8192
// (1/sqrt(32)) * log2(e): folded into Q so softmax is pure exp2
#define QSCALE 0.2550120651552454f
#define EXP2(x) __builtin_amdgcn_exp2f(x)

__device__ __forceinline__ void async16(const u16* g, u16* l) {
    __builtin_amdgcn_global_load_lds(
        (const __attribute__((address_space(1))) u32*)g,
        (__attribute__((address_space(3))) u32*)l, 16, 0, 0);
}
// pack 2 floats -> 2 bf16 (round-half-up): 2 adds + v_perm
__device__ __forceinline__ u32 pkbf(float a, float b) {
    u32 ua = __float_as_uint(a) + 0x8000u;
    u32 ub = __float_as_uint(b) + 0x8000u;
    return __builtin_amdgcn_perm(ub, ua, 0x07060302u);  // [ub.b3 ub.b2 ua.b3 ua.b2]
}
__device__ __forceinline__ u16 bf1(float a) {
    return (u16)((__float_as_uint(a) + 0x8000u) >> 16);
}

// ---------------- LayerNorm: one wave per row, bf16 output -----------------
__global__ __launch_bounds__(256) void ln_bf(const float* __restrict__ in,
        u16* __restrict__ out, const float* __restrict__ gamma,
        const float* __restrict__ beta) {
    int row  = blockIdx.x * 4 + (threadIdx.x >> 6);
    int lane = threadIdx.x & 63;
    float4 v = ((const float4*)(in + (size_t)row * TE))[lane];
    float s  = v.x + v.y + v.z + v.w;
    float s2 = v.x*v.x + v.y*v.y + v.z*v.z + v.w*v.w;
    #pragma unroll
    for (int off = 32; off > 0; off >>= 1) {
        s  += __shfl_down(s,  off, 64);
        s2 += __shfl_down(s2, off, 64);
    }
    s  = __shfl(s,  0, 64);
    s2 = __shfl(s2, 0, 64);
    float mu = s * (1.f / TE);
    float rs = rsqrtf(s2 * (1.f / TE) - mu * mu + 1e-5f);
    float4 g = ((const float4*)gamma)[lane];
    float4 b = ((const float4*)beta )[lane];
    u32 lo = pkbf((v.x - mu) * rs * g.x + b.x, (v.y - mu) * rs * g.y + b.y);
    u32 hi = pkbf((v.z - mu) * rs * g.z + b.z, (v.w - mu) * rs * g.w + b.w);
    ((uint2*)(out + (size_t)row * TE))[lane] = make_uint2(lo, hi);
}

// -------------- convert the 4 weight matrices fp32 -> bf16 -----------------
__global__ __launch_bounds__(256) void convw(const float* __restrict__ s0, u16* d0,
        const float* __restrict__ s1, u16* d1, const float* __restrict__ s2, u16* d2,
        const float* __restrict__ s3, u16* d3) {
    int i = (blockIdx.x * 256 + threadIdx.x) * 4;
    const float* s; u16* d;
    if      (i < 196608) { s = s0; d = d0; }
    else if (i < 262144) { s = s1; d = d1; i -= 196608; }
    else if (i < 524288) { s = s2; d = d2; i -= 262144; }
    else                 { s = s3; d = d3; i -= 524288; }
    float4 v = *(const float4*)(s + i);
    *(uint2*)(d + i) = make_uint2(pkbf(v.x, v.y), pkbf(v.z, v.w));
}

// ------------------- MFMA GEMM: C[N,M] = A[N,K] @ W[M,K]^T -----------------
// BK=64 staged as two 32-halves per barrier pair (half the barrier drains).
// BM=BN=128: 4 waves x (64tok x 64feat). BM=BN=64: 4 waves x (32tok x 32feat)
// Operands swapped (D rows=feat, cols=tok) -> lane holds 4 consecutive feats.
// EPI: 0=QKV: feat<256 -> Q bf16 [tok][256] (qscaled); 256..511 -> K frag-
// ordered [bh][tile][frag][hi][lq][8] (Kf = bias); >=512 -> V frag-ordered
// same layout (Vf = R).  1=fp32 +residual; 2=bf16 relu(acc+bias);
// 3=fp32 acc+bias+residual.
template<int K, int BM, int EPI>
__global__ __launch_bounds__(256) void mgemm(const u16* __restrict__ A,
        const u16* __restrict__ W, const float* __restrict__ bias,
        const float* __restrict__ R, float* __restrict__ Cf,
        u16* __restrict__ Cb, int M) {
    constexpr int BN = BM;                       // square tiles
    __shared__ u16 Al[2][BM * 32];
    __shared__ u16 Wl[2][BN * 32];
    const int tid = threadIdx.x, w = tid >> 6, l = tid & 63;
    const int n0 = blockIdx.y * BM;              // token base
    const int m0 = blockIdx.x * BN;              // feat base
    constexpr int NT = (BM == 128) ? 4 : 2;      // tok frags / wave
    constexpr int NF = (BM == 128) ? 4 : 2;      // feat frags / wave
    const int tw = (w & 1) * NT * 16;
    const int fw = (w >> 1) * NF * 16;
    const int fr = l & 15, fq = l >> 4;
    const int sr = l >> 2, sc = (l & 3) * 8;
    f32x4 acc[NT][NF];
    #pragma unroll
    for (int t = 0; t < NT; t++)
        #pragma unroll
        for (int f = 0; f < NF; f++)
            #pragma unroll
            for (int r = 0; r < 4; r++) acc[t][f][r] = 0.f;

    for (int k0 = 0; k0 < K; k0 += 64) {
        __syncthreads();
        #pragma unroll
        for (int hh = 0; hh < 2; hh++) {
            const int kc = k0 + hh * 32;
            if (BM == 128) {
                #pragma unroll
                for (int c = 0; c < 2; c++) {
                    int rr = (w * 2 + c) * 16 + sr;
                    async16(A + (size_t)(n0 + rr) * K + kc + sc, &Al[hh][(w * 2 + c) * 512]);
                    async16(W + (size_t)(m0 + rr) * K + kc + sc, &Wl[hh][(w * 2 + c) * 512]);
                }
            } else {
                int rr = w * 16 + sr;
                async16(A + (size_t)(n0 + rr) * K + kc + sc, &Al[hh][w * 512]);
                async16(W + (size_t)(m0 + rr) * K + kc + sc, &Wl[hh][w * 512]);
            }
        }
        __syncthreads();
        #pragma unroll
        for (int hh = 0; hh < 2; hh++) {
            bf16x8 af[NT], wf[NF];
            #pragma unroll
            for (int t = 0; t < NT; t++)
                af[t] = *(const bf16x8*)&Al[hh][(tw + t * 16 + fr) * 32 + fq * 8];
            #pragma unroll
            for (int f = 0; f < NF; f++)
                wf[f] = *(const bf16x8*)&Wl[hh][(fw + f * 16 + fr) * 32 + fq * 8];
            #pragma unroll
            for (int t = 0; t < NT; t++)
                #pragma unroll
                for (int f = 0; f < NF; f++)
                    acc[t][f] = __builtin_amdgcn_mfma_f32_16x16x32_bf16(
                        wf[f], af[t], acc[t][f], 0, 0, 0);   // D rows=feat, cols=tok
        }
    }
    // epilogue: lane holds (tok = n0+tw+t*16+fr, feats fb..fb+3)
    #pragma unroll
    for (int t = 0; t < NT; t++) {
        const int tok = n0 + tw + t * 16 + fr;
        #pragma unroll
        for (int f = 0; f < NF; f++) {
            const int fb = m0 + fw + f * 16 + fq * 4;
            f32x4 v = acc[t][f];
            if (EPI == 0) {
                if (fb < 256) {
                    *(uint2*)(Cb + (size_t)tok * 256 + fb) = make_uint2(
                        pkbf(v[0]*QSCALE, v[1]*QSCALE), pkbf(v[2]*QSCALE, v[3]*QSCALE));
                } else if (fb < 512) {
                    // K fragment-ordered: [bh][tile][frag][hi][lq][8]
                    const int hh = (fb - 256) >> 5, dd = (fb - 256) & 31;
                    const int bh = (tok >> 11) * 8 + hh;
                    const int kv = tok & 2047, tile = kv >> 5, lq = kv & 31;
                    const int fg = dd >> 4, hg = (dd >> 3) & 1, j = dd & 7;
                    u16* kp = (u16*)bias +
                        (((((size_t)bh * 64 + tile) * 2 + fg) * 2 + hg) * 32 + lq) * 8 + j;
                    *(uint2*)kp = make_uint2(pkbf(v[0], v[1]), pkbf(v[2], v[3]));
                } else {
                    // V fragment-ordered: row = d, k-chunk = kv-within-tile
                    const int hh = (fb - 512) >> 5, dd = (fb - 512) & 31;
                    const int bh = (tok >> 11) * 8 + hh;
                    const int kv = tok & 2047, tile = kv >> 5, kvr = kv & 31;
                    const int fg = kvr >> 4, hg = (kvr >> 3) & 1, j = kvr & 7;
                    u16* vp = (u16*)R +
                        ((((size_t)bh * 64 + tile) * 2 + fg) * 2 + hg) * 256 +
                        (size_t)dd * 8 + j;
                    vp[0]  = bf1(v[0]);
                    vp[8]  = bf1(v[1]);
                    vp[16] = bf1(v[2]);
                    vp[24] = bf1(v[3]);
                }
            } else if (EPI == 1) {
                float4 r4 = *(const float4*)(R + (size_t)tok * M + fb);
                *(float4*)(Cf + (size_t)tok * M + fb) =
                    make_float4(v[0]+r4.x, v[1]+r4.y, v[2]+r4.z, v[3]+r4.w);
            } else if (EPI == 2) {
                float4 b4 = *(const float4*)(bias + fb);
                *(uint2*)(Cb + (size_t)tok * M + fb) = make_uint2(
                    pkbf(fmaxf(v[0]+b4.x, 0.f), fmaxf(v[1]+b4.y, 0.f)),
                    pkbf(fmaxf(v[2]+b4.z, 0.f), fmaxf(v[3]+b4.w, 0.f)));
            } else {
                float4 b4 = *(const float4*)(bias + fb);
                float4 r4 = *(const float4*)(R + (size_t)tok * M + fb);
                *(float4*)(Cf + (size_t)tok * M + fb) = make_float4(
                    v[0]+b4.x+r4.x, v[1]+b4.y+r4.y, v[2]+b4.z+r4.z, v[3]+b4.w+r4.w);
            }
        }
    }
}

// ------------- MFMA flash attention, in-register softmax (T12) -------------
// 32x32x16 MFMAs, swapped QK^T (mfma(K,Q)): lane (col=q=l&31) holds 16 P
// values (rows kv=(reg&3)+8*(reg>>2)+4*(l>>5)).  P -> bf16 PV-fragment fully
// in-register: 8 v_cvt_pk_bf16_f32 + 4 v_permlane32_swap_b32 (no P LDS).
// K and V live in global pre-fragmented MFMA order (written by the QKV GEMM
// epilogue): each fragment load is one fully-coalesced 1KB wave load at
// kp + l*16B.  Rotating 1-tile register prefetch hides L2 latency under the
// exp2/pack/MFMA work.  No LDS / barriers in the main loop.  kv-split 2:
// waves (qw=w&1, kw=w>>1); unnormalized partials merge by addition in LDS.
// Block swizzle pins all 32 blocks of one (b,h) to a single XCD (L2 reuse).
__global__ __launch_bounds__(256, 4) void attn_k(const u16* __restrict__ qb,
        const u16* __restrict__ kfb, const u16* __restrict__ vfb,
        u16* __restrict__ attn) {
    const int id = blockIdx.x;                 // 1024 blocks
    const int bh   = (id & 7) * 4 + (id >> 8); // xcd*4 + group
    const int tile = (id >> 3) & 31;           // 64-q tile within bh
    const int b = bh >> 3, h = bh & 7;
    const int tid = threadIdx.x, w = tid >> 6, l = tid & 63;
    const int qw = w & 1, kw = w >> 1;
    const int lq = l & 31, hi = l >> 5;
    const size_t btok = (size_t)b * TS;
    const int q0 = tile * 64 + qw * 32;

    __shared__ float mrg[2304];                // 2 x 64 lanes x 18 f32

    // Q frags: B-op [col=q=l&31][k=d=(l>>5)*8..+8], pre-scaled by QSCALE
    const u16* qrow = qb + (btok + q0 + lq) * 256 + h * 32 + hi * 8;
    bf16x8 qf0 = *(const bf16x8*)qrow;         // d 0..16
    bf16x8 qf1 = *(const bf16x8*)(qrow + 16);  // d 16..32

    f32x16 zf, o;
    #pragma unroll
    for (int r = 0; r < 16; r++) { zf[r] = 0.f; o[r] = 0.f; }
    float ps = 0.f;

    // fragment streams: 1024 u16 per 32-kv tile, lane l owns bytes l*16..+16
    const u16* kp = kfb + ((size_t)bh * 64 + kw * 32) * 1024 + l * 8;
    const u16* vp = vfb + ((size_t)bh * 64 + kw * 32) * 1024 + l * 8;
    bf16x8 k0 = *(const bf16x8*)kp;
    bf16x8 k1 = *(const bf16x8*)(kp + 512);
    bf16x8 v0 = *(const bf16x8*)vp;
    bf16x8 v1 = *(const bf16x8*)(vp + 512);

    #pragma unroll 2
    for (int it = 0; it < 32; ++it) {
        kp += 1024; vp += 1024;
        // prefetch next tile (last iter reads 1 tile past end -> in-ws, unused)
        bf16x8 nk0 = *(const bf16x8*)kp;
        bf16x8 nk1 = *(const bf16x8*)(kp + 512);
        bf16x8 nv0 = *(const bf16x8*)vp;
        bf16x8 nv1 = *(const bf16x8*)(vp + 512);
        // S[kv][q] (col=q): two chained MFMAs cover d=32
        f32x16 p = __builtin_amdgcn_mfma_f32_32x32x16_bf16(k0, qf0, zf, 0, 0, 0);
        p = __builtin_amdgcn_mfma_f32_32x32x16_bf16(k1, qf1, p, 0, 0, 0);
        float e[16];
        #pragma unroll
        for (int r = 0; r < 16; r++) e[r] = EXP2(p[r]);
        ps += ((e[0]+e[1]) + (e[2]+e[3])) + ((e[4]+e[5]) + (e[6]+e[7]))
            + ((e[8]+e[9]) + (e[10]+e[11])) + ((e[12]+e[13]) + (e[14]+e[15]));
        // pack: a[j] = bf16(e[2j]) | bf16(e[2j+1])<<16  (kv-consecutive pairs)
        u32 a[8];
        #pragma unroll
        for (int j = 0; j < 8; j++)
            asm("v_cvt_pk_bf16_f32 %0, %1, %2"
                : "=v"(a[j]) : "v"(e[2*j]), "v"(e[2*j+1]));
        // redistribute across lane halves: (w0,w2)=swap(a0,a2) etc (T12)
        asm("v_permlane32_swap_b32 %0, %1" : "+v"(a[0]), "+v"(a[2]));
        asm("v_permlane32_swap_b32 %0, %1" : "+v"(a[1]), "+v"(a[3]));
        asm("v_permlane32_swap_b32 %0, %1" : "+v"(a[4]), "+v"(a[6]));
        asm("v_permlane32_swap_b32 %0, %1" : "+v"(a[5]), "+v"(a[7]));
        u32v4 t0 = {a[0], a[1], a[2], a[3]};   // P^T[q][kv0+hi*8 .. +8]
        u32v4 t1 = {a[4], a[5], a[6], a[7]};   // P^T[q][kv0+16+hi*8 .. +8]
        bf16x8 pf0 = __builtin_bit_cast(bf16x8, t0);
        bf16x8 pf1 = __builtin_bit_cast(bf16x8, t1);
        // O^T[d][q] += V^T * P^T
        o = __builtin_amdgcn_mfma_f32_32x32x16_bf16(v0, pf0, o, 0, 0, 0);
        o = __builtin_amdgcn_mfma_f32_32x32x16_bf16(v1, pf1, o, 0, 0, 0);
        k0 = nk0; k1 = nk1; v0 = nv0; v1 = nv1;
    }
    // lane l and l+32 (same q) cover complementary kv rows -> full half-sum
    ps += __shfl_xor(ps, 32, 64);

    // merge the two kv halves: kw=1 dumps (o, ps); kw=0 adds + stores
    if (kw == 1) {
        float* d = mrg + (qw * 64 + l) * 18;
        #pragma unroll
        for (int r = 0; r < 16; r++) d[r] = o[r];
        d[16] = ps;
    }
    __syncthreads();
    if (kw == 0) {
        const float* d = mrg + (qw * 64 + l) * 18;
        #pragma unroll
        for (int r = 0; r < 16; r++) o[r] += d[r];
        ps += d[16];
        float inv = 1.f / ps;
        // o reg r -> d = 8*(r>>2) + 4*hi + (r&3); q = lq
        int tok = (int)btok + q0 + lq;
        u16* orow = attn + (size_t)tok * 256 + h * 32 + hi * 4;
        #pragma unroll
        for (int g = 0; g < 4; g++)
            *(uint2*)(orow + g * 8) = make_uint2(
                pkbf(o[4*g]*inv, o[4*g+1]*inv), pkbf(o[4*g+2]*inv, o[4*g+3]*inv));
    }
}

extern "C" void kernel_launch(void* const* d_in, const int* in_sizes, int n_in,
                              void* d_out, int out_size, void* d_ws, size_t ws_size,
                              hipStream_t stream) {
    const float* src  = (const float*)d_in[0];
    const float* w_in = (const float*)d_in[1];
    const float* w_out= (const float*)d_in[2];
    const float* w1   = (const float*)d_in[3];
    const float* b1   = (const float*)d_in[4];
    const float* w2   = (const float*)d_in[5];
    const float* b2   = (const float*)d_in[6];
    const float* g1   = (const float*)d_in[7];
    const float* be1  = (const float*)d_in[8];
    const float* g2   = (const float*)d_in[9];
    const float* be2  = (const float*)d_in[10];
    float* out = (float*)d_out;

    u16* xb    = (u16*)d_ws;                       // [0, 4MB)    8192 x 256
    u16* qb    = xb + (size_t)NTOK * 256;          // [4, 8MB)    8192 x 256 Q
    u16* kfbuf = qb + (size_t)NTOK * 256;          // [8, 12MB)   K frags
    u16* vfbuf = kfbuf + (size_t)32 * 64 * 1024;   // [12, 16MB)  V frags
    u16* attnb = xb;                               // reuse (xb dead after G2)
    u16* h1b   = (u16*)d_ws;                       // 8192*1024 (after attn GEMMs)
    u16* x2b   = (u16*)((char*)d_ws + (size_t)NTOK * 1024 * 2);
    u16* wib   = x2b + (size_t)NTOK * 256;
    u16* wob   = wib + 768 * 256;
    u16* w1b   = wob + 256 * 256;
    u16* w2b   = w1b + 1024 * 256;

    convw<<<768, 256, 0, stream>>>(w_in, wib, w_out, wob, w1, w1b, w2, w2b);
    // 1. xb = LN1(src) -> bf16
    ln_bf<<<NTOK / 4, 256, 0, stream>>>(src, xb, g1, be1);
    // 2. qb = Q (scaled), kfbuf/vfbuf = K,V fragment-ordered  (= xb @ w_in^T)
    mgemm<256, 128, 0><<<dim3(6, 64), 256, 0, stream>>>(
        xb, wib, (const float*)kfbuf, (const float*)vfbuf, nullptr, qb, 768);
    // 3. attnb = flash-attention(qb, kfbuf, vfbuf)
    attn_k<<<dim3(1024), 256, 0, stream>>>(qb, kfbuf, vfbuf, attnb);
    // 4. out = src + attnb @ w_out^T (fp32)
    mgemm<256, 64, 1><<<dim3(4, 128), 256, 0, stream>>>(
        attnb, wob, nullptr, src, out, nullptr, 256);
    // 5. x2b = LN2(out) -> bf16
    ln_bf<<<NTOK / 4, 256, 0, stream>>>(out, x2b, g2, be2);
    // 6. h1b = relu(x2b @ w1^T + b1) -> bf16
    mgemm<256, 128, 2><<<dim3(8, 64), 256, 0, stream>>>(
        x2b, w1b, b1, nullptr, nullptr, h1b, 1024);
    // 7. out = out + h1b @ w2^T + b2 (fp32)
    mgemm<1024, 64, 3><<<dim3(4, 128), 256, 0, stream>>>(
        h1b, w2b, b2, out, out, nullptr, 256);
}